// Round 12
// baseline (61.669 us; speedup 1.0000x reference)
//
#include <hip/hip_runtime.h>
#include <math.h>

#define VOCAB   50265
#define D       768
#define N_NEW   200
#define N_NODES 199
#define N_EDGES 1024
#define LEAKY   0.2f

typedef float f4 __attribute__((ext_vector_type(4)));

// ---- GEMM split-K config (f4 cols: 192 working threads cover 768 cols) ----
#define ROW_T 4
#define KC    8
#define KLEN  96                  // 768/KC
#define NROWT 50                  // ceil(199/4)
#define NB_GEMM (NROWT * KC)      // 400
// partial[kc][row][col]; svp/dvp[row][kc] (199*8)

// ---------------- L1: hybrid — gemm blocks + gather blocks
__global__ __launch_bounds__(256) void hybrid_kernel(
    const int* __restrict__ x, const float* __restrict__ orig_emb,
    const float* __restrict__ new_emb, const float* __restrict__ W,
    const float* __restrict__ a_src, const float* __restrict__ a_dst,
    float* __restrict__ partial, float* __restrict__ svp, float* __restrict__ dvp,
    float* __restrict__ out, int* __restrict__ gcnt, int* __restrict__ glist,
    int ntok)
{
    const int tid = threadIdx.x;
    const int bid = blockIdx.x;

    if (bid < NB_GEMM) {
        // ================= GEMM partial (f4 over cols) =================
        __shared__ float fts[ROW_T][KLEN];
        __shared__ float rS[ROW_T][3], rD[ROW_T][3];
        const int rowt = bid % NROWT;
        const int kc   = bid / NROWT;
        const int row0 = rowt * ROW_T;
        const int k0   = kc * KLEN;
        const int lane = tid & 63, wid = tid >> 6;

        for (int i = tid; i < ROW_T * KLEN; i += 256) {
            int r  = i / KLEN;
            int kk = i - r * KLEN;
            int row = row0 + r;
            fts[r][kk] = (row < N_NODES) ? new_emb[(size_t)(1 + row) * D + k0 + kk] : 0.f;
        }
        __syncthreads();

        if (tid < 192) {
            const f4* Wf4 = (const f4*)W;
            f4 acc[ROW_T];
            #pragma unroll
            for (int r = 0; r < ROW_T; ++r) acc[r] = (f4){0.f, 0.f, 0.f, 0.f};

            #pragma unroll 4
            for (int kk = 0; kk < KLEN; ++kk) {
                const f4 w = Wf4[(size_t)(k0 + kk) * 192 + tid];
                #pragma unroll
                for (int r = 0; r < ROW_T; ++r)
                    acc[r] += fts[r][kk] * w;
            }

            #pragma unroll
            for (int r = 0; r < ROW_T; ++r) {
                const int row = row0 + r;
                if (row < N_NODES)
                    ((f4*)(partial + ((size_t)kc * N_NODES + row) * D))[tid] = acc[r];
            }

            const f4 as = ((const f4*)a_src)[tid];
            const f4 ad = ((const f4*)a_dst)[tid];
            #pragma unroll
            for (int r = 0; r < ROW_T; ++r) {
                float ps = acc[r].x * as.x + acc[r].y * as.y + acc[r].z * as.z + acc[r].w * as.w;
                float pd = acc[r].x * ad.x + acc[r].y * ad.y + acc[r].z * ad.z + acc[r].w * ad.w;
                #pragma unroll
                for (int off = 32; off; off >>= 1) {
                    ps += __shfl_down(ps, off, 64);
                    pd += __shfl_down(pd, off, 64);
                }
                if (lane == 0) { rS[r][wid] = ps; rD[r][wid] = pd; }
            }
        }
        __syncthreads();
        if (tid < ROW_T) {
            const int row = row0 + tid;
            if (row < N_NODES) {
                svp[row * KC + kc] = rS[tid][0] + rS[tid][1] + rS[tid][2];
                dvp[row * KC + kc] = rD[tid][0] + rD[tid][1] + rD[tid][2];
            }
        }
        return;
    }

    // ================= Gather (non-graph tokens) =================
    const int token = (bid - NB_GEMM) * 4 + (tid >> 6);
    if (token >= ntok) return;
    const int lane = tid & 63;
    const int idx = x[token];

    if (idx >= VOCAB && idx < VOCAB + N_NODES) {
        if (lane == 0) {
            int pos = atomicAdd(gcnt, 1);
            glist[pos] = token;
        }
        return;
    }

    const f4* src = (idx < VOCAB)
        ? (const f4*)(orig_emb + (size_t)idx * D)
        : (const f4*)(new_emb + (size_t)N_NEW * D);

    f4* dst = (f4*)(out + (size_t)token * D);
    f4 v0 = src[lane];
    f4 v1 = src[lane + 64];
    f4 v2 = src[lane + 128];
    __builtin_nontemporal_store(v0, &dst[lane]);
    __builtin_nontemporal_store(v1, &dst[lane + 64]);
    __builtin_nontemporal_store(v2, &dst[lane + 128]);
}

// ---------------- L2: per-node softmax + aggregate + direct out-write
__global__ __launch_bounds__(256) void softagg_out_kernel(
    const int* __restrict__ x, const int* __restrict__ edge_index,
    const float* __restrict__ svp, const float* __restrict__ dvp,
    const float* __restrict__ partial, const float* __restrict__ new_emb,
    const int* __restrict__ gcnt, const int* __restrict__ glist,
    float* __restrict__ out)
{
    __shared__ float sv_l[N_NODES], dv_l[N_NODES];
    __shared__ float e[N_EDGES];
    __shared__ short ssrc[N_EDGES];
    __shared__ short ml[N_EDGES];
    __shared__ int   wsum[4];
    __shared__ int   s_total;
    __shared__ int   t_tok[256];
    __shared__ short t_node[256];
    const int n   = blockIdx.x;
    const int tid = threadIdx.x;
    const int lane = tid & 63, wid = tid >> 6;

    for (int i = tid; i < N_NODES; i += 256) {
        float s = 0.f, d = 0.f;
        #pragma unroll
        for (int q = 0; q < KC; ++q) {
            s += svp[i * KC + q];
            d += dvp[i * KC + q];
        }
        sv_l[i] = s;
        dv_l[i] = d;
    }
    __syncthreads();

    const int4 se = ((const int4*)edge_index)[tid];
    const int4 de = ((const int4*)(edge_index + N_EDGES))[tid];
    const int srcs[4] = { se.x, se.y, se.z, se.w };
    const int dsts[4] = { de.x, de.y, de.z, de.w };

    int mycnt = 0;
    #pragma unroll
    for (int j = 0; j < 4; ++j) {
        const int k = 4 * tid + j;
        float ev = sv_l[srcs[j]] + dv_l[dsts[j]];
        e[k] = ev > 0.f ? ev : LEAKY * ev;
        ssrc[k] = (short)srcs[j];
        if (dsts[j] == n) ++mycnt;
    }

    int pre = mycnt;
    #pragma unroll
    for (int off = 1; off < 64; off <<= 1) {
        int v = __shfl_up(pre, off, 64);
        if (lane >= off) pre += v;
    }
    if (lane == 63) wsum[wid] = pre;
    __syncthreads();
    int woff = 0;
    for (int w = 0; w < wid; ++w) woff += wsum[w];
    int base = woff + pre - mycnt;
    #pragma unroll
    for (int j = 0; j < 4; ++j) {
        if (dsts[j] == n) ml[base++] = (short)(4 * tid + j);
    }
    if (tid == 255) s_total = woff + pre;
    __syncthreads();

    const int c = s_total;

    float mx = -INFINITY;
    for (int p = 0; p < c; ++p) mx = fmaxf(mx, e[ml[p]]);
    float dn = 0.f;
    for (int p = 0; p < c; ++p) dn += expf(e[ml[p]] - mx);
    const float inv = 1.f / fmaxf(dn, 1e-9f);

    const size_t kcstride = (size_t)N_NODES * D;
    float a0 = 0.f, a1 = 0.f, a2 = 0.f;
    for (int p = 0; p < c; ++p) {
        const int k = ml[p];
        const float a = expf(e[k] - mx) * inv;
        const float* pb = partial + (size_t)ssrc[k] * D;
        float h0 = 0.f, h1 = 0.f, h2 = 0.f;
        #pragma unroll
        for (int q = 0; q < KC; ++q) {
            h0 += pb[q * kcstride + tid];
            h1 += pb[q * kcstride + tid + 256];
            h2 += pb[q * kcstride + tid + 512];
        }
        a0 = fmaf(a, h0, a0);
        a1 = fmaf(a, h1, a1);
        a2 = fmaf(a, h2, a2);
    }
    const float* f = new_emb + (size_t)(1 + n) * D;
    const float e0 = (a0 > 0.f ? a0 : expf(a0) - 1.f) + f[tid];
    const float e1 = (a1 > 0.f ? a1 : expf(a1) - 1.f) + f[tid + 256];
    const float e2 = (a2 > 0.f ? a2 : expf(a2) - 1.f) + f[tid + 512];

    // direct out-writes for this node's tokens (glist staged via LDS)
    const int cnt = *gcnt;
    for (int b = 0; b < cnt; b += 256) {
        const int p = b + tid;
        int tok = -1, nd = -1;
        if (p < cnt) { tok = glist[p]; nd = x[tok] - VOCAB; }
        t_tok[tid] = tok;
        t_node[tid] = (short)nd;
        __syncthreads();
        const int lim = min(256, cnt - b);
        for (int q = 0; q < lim; ++q) {
            if ((int)t_node[q] == n) {
                float* o = out + (size_t)t_tok[q] * D;
                o[tid]       = e0;
                o[tid + 256] = e1;
                o[tid + 512] = e2;
            }
        }
        __syncthreads();
    }
}

extern "C" void kernel_launch(void* const* d_in, const int* in_sizes, int n_in,
                              void* d_out, int out_size, void* d_ws, size_t ws_size,
                              hipStream_t stream) {
    const int*   x        = (const int*)  d_in[0];
    const float* orig_emb = (const float*)d_in[1];
    const float* new_emb  = (const float*)d_in[2];
    const float* W        = (const float*)d_in[3];
    const float* a_src    = (const float*)d_in[4];
    const float* a_dst    = (const float*)d_in[5];
    const int*   edge_idx = (const int*)  d_in[6];
    float* out = (float*)d_out;

    // workspace layout
    int*   gcnt    = (int*)d_ws;                               // counter
    float* partial = (float*)((char*)d_ws + 256);              // KC*199*768
    float* svp     = partial + (size_t)KC * N_NODES * D;       // 199*KC
    float* dvp     = svp + N_NODES * KC;                       // 199*KC
    int*   glist   = (int*)(dvp + N_NODES * KC);               // up to ntok

    const int ntok = in_sizes[0];                              // 32768
    const int nblocks = NB_GEMM + (ntok + 3) / 4;              // 400 + 8192

    hipMemsetAsync(gcnt, 0, 16, stream);
    hybrid_kernel<<<nblocks, 256, 0, stream>>>(
        x, orig_emb, new_emb, W, a_src, a_dst,
        partial, svp, dvp, out, gcnt, glist, ntok);
    softagg_out_kernel<<<N_NODES, 256, 0, stream>>>(
        x, edge_idx, svp, dvp, partial, new_emb, gcnt, glist, out);
}

// Round 13
// 60.850 us; speedup vs baseline: 1.0134x; 1.0134x over previous
//
#include <hip/hip_runtime.h>
#include <math.h>

#define VOCAB   50265
#define D       768
#define N_NEW   200
#define N_NODES 199
#define N_EDGES 1024
#define LEAKY   0.2f

typedef float f4 __attribute__((ext_vector_type(4)));

// ---- GEMM split-K config ----
#define ROW_T 4
#define KC    8
#define KLEN  96                  // 768/KC
#define NROWT 50                  // ceil(199/4)
#define NCH   (KC * 3)            // svp/dvp slots per row (24)
#define NB_GEMM (NROWT * 3 * KC)  // 1200

// ---------------- L1: hybrid — gemm blocks + gather blocks (round-11 proven)
__global__ __launch_bounds__(256) void hybrid_kernel(
    const int* __restrict__ x, const float* __restrict__ orig_emb,
    const float* __restrict__ new_emb, const float* __restrict__ W,
    const float* __restrict__ a_src, const float* __restrict__ a_dst,
    float* __restrict__ partial, float* __restrict__ svp, float* __restrict__ dvp,
    float* __restrict__ out, int* __restrict__ gcnt, int* __restrict__ glist,
    int ntok)
{
    const int tid = threadIdx.x;
    const int bid = blockIdx.x;

    if (bid < NB_GEMM) {
        // ================= GEMM partial =================
        __shared__ float fts[ROW_T][KLEN];
        __shared__ float rS[ROW_T][4], rD[ROW_T][4];
        const int rowt = bid % NROWT;
        const int colt = (bid / NROWT) % 3;
        const int kc   = bid / (NROWT * 3);
        const int row0 = rowt * ROW_T;
        const int col  = colt * 256 + tid;
        const int k0   = kc * KLEN;
        const int lane = tid & 63, wid = tid >> 6;

        for (int i = tid; i < ROW_T * KLEN; i += 256) {
            int r  = i / KLEN;
            int kk = i - r * KLEN;
            int row = row0 + r;
            fts[r][kk] = (row < N_NODES) ? new_emb[(size_t)(1 + row) * D + k0 + kk] : 0.f;
        }
        __syncthreads();

        float acc[ROW_T] = {0.f, 0.f, 0.f, 0.f};
        #pragma unroll 4
        for (int kk = 0; kk < KLEN; ++kk) {
            float w = W[(size_t)(k0 + kk) * D + col];
            #pragma unroll
            for (int r = 0; r < ROW_T; ++r)
                acc[r] = fmaf(fts[r][kk], w, acc[r]);
        }

        const size_t base = ((size_t)kc * N_NODES) * D + col;
        #pragma unroll
        for (int r = 0; r < ROW_T; ++r)
            if (row0 + r < N_NODES) partial[base + (size_t)(row0 + r) * D] = acc[r];

        const float as = a_src[col];
        const float ad = a_dst[col];
        #pragma unroll
        for (int r = 0; r < ROW_T; ++r) {
            float ps = acc[r] * as;
            float pd = acc[r] * ad;
            #pragma unroll
            for (int off = 32; off; off >>= 1) {
                ps += __shfl_down(ps, off, 64);
                pd += __shfl_down(pd, off, 64);
            }
            if (lane == 0) { rS[r][wid] = ps; rD[r][wid] = pd; }
        }
        __syncthreads();
        if (tid < ROW_T) {
            const int row = row0 + tid;
            if (row < N_NODES) {
                const int slot = row * NCH + kc * 3 + colt;
                svp[slot] = rS[tid][0] + rS[tid][1] + rS[tid][2] + rS[tid][3];
                dvp[slot] = rD[tid][0] + rD[tid][1] + rD[tid][2] + rD[tid][3];
            }
        }
        return;
    }

    // ================= Gather (non-graph tokens) =================
    const int token = (bid - NB_GEMM) * 4 + (tid >> 6);
    if (token >= ntok) return;
    const int lane = tid & 63;
    const int idx = x[token];

    if (idx >= VOCAB && idx < VOCAB + N_NODES) {
        if (lane == 0) {
            int pos = atomicAdd(gcnt, 1);
            glist[pos] = token;
        }
        return;
    }

    const f4* src = (idx < VOCAB)
        ? (const f4*)(orig_emb + (size_t)idx * D)
        : (const f4*)(new_emb + (size_t)N_NEW * D);

    f4* dst = (f4*)(out + (size_t)token * D);
    f4 v0 = src[lane];
    f4 v1 = src[lane + 64];
    f4 v2 = src[lane + 128];
    __builtin_nontemporal_store(v0, &dst[lane]);
    __builtin_nontemporal_store(v1, &dst[lane + 64]);
    __builtin_nontemporal_store(v2, &dst[lane + 128]);
}

// ---------------- L2: per-node softmax + aggregate + direct out-write
__global__ __launch_bounds__(256) void softagg_out_kernel(
    const int* __restrict__ x, const int* __restrict__ edge_index,
    const float* __restrict__ svp, const float* __restrict__ dvp,
    const float* __restrict__ partial, const float* __restrict__ new_emb,
    const int* __restrict__ gcnt, const int* __restrict__ glist,
    float* __restrict__ out)
{
    __shared__ float sv_l[N_NODES], dv_l[N_NODES];
    __shared__ float e[N_EDGES];
    __shared__ short ssrc[N_EDGES];
    __shared__ short ml[N_EDGES];
    __shared__ int   wsum[4];
    __shared__ int   s_total;
    __shared__ int   t_tok[256];
    __shared__ short t_node[256];
    const int n   = blockIdx.x;
    const int tid = threadIdx.x;
    const int lane = tid & 63, wid = tid >> 6;

    for (int i = tid; i < N_NODES; i += 256) {
        float s = 0.f, d = 0.f;
        #pragma unroll
        for (int q = 0; q < NCH; ++q) {
            s += svp[i * NCH + q];
            d += dvp[i * NCH + q];
        }
        sv_l[i] = s;
        dv_l[i] = d;
    }
    __syncthreads();

    const int4 se = ((const int4*)edge_index)[tid];
    const int4 de = ((const int4*)(edge_index + N_EDGES))[tid];
    const int srcs[4] = { se.x, se.y, se.z, se.w };
    const int dsts[4] = { de.x, de.y, de.z, de.w };

    int mycnt = 0;
    #pragma unroll
    for (int j = 0; j < 4; ++j) {
        const int k = 4 * tid + j;
        float ev = sv_l[srcs[j]] + dv_l[dsts[j]];
        e[k] = ev > 0.f ? ev : LEAKY * ev;
        ssrc[k] = (short)srcs[j];
        if (dsts[j] == n) ++mycnt;
    }

    int pre = mycnt;
    #pragma unroll
    for (int off = 1; off < 64; off <<= 1) {
        int v = __shfl_up(pre, off, 64);
        if (lane >= off) pre += v;
    }
    if (lane == 63) wsum[wid] = pre;
    __syncthreads();
    int woff = 0;
    for (int w = 0; w < wid; ++w) woff += wsum[w];
    int base = woff + pre - mycnt;
    #pragma unroll
    for (int j = 0; j < 4; ++j) {
        if (dsts[j] == n) ml[base++] = (short)(4 * tid + j);
    }
    if (tid == 255) s_total = woff + pre;
    __syncthreads();

    const int c = s_total;

    float mx = -INFINITY;
    for (int p = 0; p < c; ++p) mx = fmaxf(mx, e[ml[p]]);
    float dn = 0.f;
    for (int p = 0; p < c; ++p) dn += expf(e[ml[p]] - mx);
    const float inv = 1.f / fmaxf(dn, 1e-9f);

    const size_t kcstride = (size_t)N_NODES * D;
    float a0 = 0.f, a1 = 0.f, a2 = 0.f;
    for (int p = 0; p < c; ++p) {
        const int k = ml[p];
        const float a = expf(e[k] - mx) * inv;
        const float* pb = partial + (size_t)ssrc[k] * D;
        float h0 = 0.f, h1 = 0.f, h2 = 0.f;
        #pragma unroll
        for (int q = 0; q < KC; ++q) {
            h0 += pb[q * kcstride + tid];
            h1 += pb[q * kcstride + tid + 256];
            h2 += pb[q * kcstride + tid + 512];
        }
        a0 = fmaf(a, h0, a0);
        a1 = fmaf(a, h1, a1);
        a2 = fmaf(a, h2, a2);
    }
    const float* f = new_emb + (size_t)(1 + n) * D;
    const float e0 = (a0 > 0.f ? a0 : expf(a0) - 1.f) + f[tid];
    const float e1 = (a1 > 0.f ? a1 : expf(a1) - 1.f) + f[tid + 256];
    const float e2 = (a2 > 0.f ? a2 : expf(a2) - 1.f) + f[tid + 512];

    // direct out-writes for this node's tokens (glist staged via LDS)
    const int cnt = *gcnt;
    for (int b = 0; b < cnt; b += 256) {
        const int p = b + tid;
        int tok = -1, nd = -1;
        if (p < cnt) { tok = glist[p]; nd = x[tok] - VOCAB; }
        t_tok[tid] = tok;
        t_node[tid] = (short)nd;
        __syncthreads();
        const int lim = min(256, cnt - b);
        for (int q = 0; q < lim; ++q) {
            if ((int)t_node[q] == n) {
                float* o = out + (size_t)t_tok[q] * D;
                o[tid]       = e0;
                o[tid + 256] = e1;
                o[tid + 512] = e2;
            }
        }
        __syncthreads();
    }
}

extern "C" void kernel_launch(void* const* d_in, const int* in_sizes, int n_in,
                              void* d_out, int out_size, void* d_ws, size_t ws_size,
                              hipStream_t stream) {
    const int*   x        = (const int*)  d_in[0];
    const float* orig_emb = (const float*)d_in[1];
    const float* new_emb  = (const float*)d_in[2];
    const float* W        = (const float*)d_in[3];
    const float* a_src    = (const float*)d_in[4];
    const float* a_dst    = (const float*)d_in[5];
    const int*   edge_idx = (const int*)  d_in[6];
    float* out = (float*)d_out;

    // workspace layout
    int*   gcnt    = (int*)d_ws;                               // counter
    float* partial = (float*)((char*)d_ws + 256);              // KC*199*768
    float* svp     = partial + (size_t)KC * N_NODES * D;       // 199*NCH
    float* dvp     = svp + N_NODES * NCH;                      // 199*NCH
    int*   glist   = (int*)(dvp + N_NODES * NCH);              // up to ntok

    const int ntok = in_sizes[0];                              // 32768
    const int nblocks = NB_GEMM + (ntok + 3) / 4;              // 1200 + 8192

    hipMemsetAsync(gcnt, 0, 16, stream);
    hybrid_kernel<<<nblocks, 256, 0, stream>>>(
        x, orig_emb, new_emb, W, a_src, a_dst,
        partial, svp, dvp, out, gcnt, glist, ntok);
    softagg_out_kernel<<<N_NODES, 256, 0, stream>>>(
        x, edge_idx, svp, dvp, partial, new_emb, gcnt, glist, out);
}